// Round 1
// baseline (495.754 us; speedup 1.0000x reference)
//
#include <hip/hip_runtime.h>

#define NPTS 400000
#define KTAPS 9
#define BN_EPS 1e-5f

// One thread per point. acc[32] in VGPRs. Weights W[k][c][32] read at
// wave-uniform addresses (expect SMEM s_load -> scalar pipe). Gathered
// feature rows read as float4 (64B/128B per row, L2/L3-cached).
template<int C, bool ADD>
__global__ __launch_bounds__(256) void conv_bn_relu(
    const float* __restrict__ feat,   // [NPTS][C]
    const int*   __restrict__ nbr,    // [NPTS][9]
    const float* __restrict__ W,      // [9][C][32]
    const float* __restrict__ gamma,  // [32] (row pre-offset)
    const float* __restrict__ beta,
    const float* __restrict__ mean,
    const float* __restrict__ var,
    float* __restrict__ out)          // [NPTS][32]; if ADD, holds addend on entry
{
    int n = blockIdx.x * blockDim.x + threadIdx.x;
    if (n >= NPTS) return;

    float acc[32];
    #pragma unroll
    for (int o = 0; o < 32; ++o) acc[o] = 0.f;

    const int* nr = nbr + n * KTAPS;

    #pragma unroll 1   // keep k-loop rolled: C=32 body is ~1k FMAs (I$ budget)
    for (int k = 0; k < KTAPS; ++k) {
        int idx = nr[k];
        if (idx >= NPTS) continue;    // idx == NPTS -> zero pad row, skip
        const float* fr = feat + (long)idx * C;
        float f[C];
        #pragma unroll
        for (int c4 = 0; c4 < C/4; ++c4) {
            float4 v = *reinterpret_cast<const float4*>(fr + c4*4);
            f[c4*4+0] = v.x; f[c4*4+1] = v.y; f[c4*4+2] = v.z; f[c4*4+3] = v.w;
        }
        const float* wk = W + k * C * 32;
        #pragma unroll
        for (int c = 0; c < C; ++c) {
            const float* wr = wk + c * 32;
            #pragma unroll
            for (int o4 = 0; o4 < 8; ++o4) {
                float4 w4 = *reinterpret_cast<const float4*>(wr + o4*4);
                acc[o4*4+0] = fmaf(f[c], w4.x, acc[o4*4+0]);
                acc[o4*4+1] = fmaf(f[c], w4.y, acc[o4*4+1]);
                acc[o4*4+2] = fmaf(f[c], w4.z, acc[o4*4+2]);
                acc[o4*4+3] = fmaf(f[c], w4.w, acc[o4*4+3]);
            }
        }
    }

    // BN (eval) + ReLU epilogue: y = relu(acc*s + (beta - mean*s)), s = gamma*rsqrt(var+eps)
    float* orow = out + (long)n * 32;
    #pragma unroll
    for (int o4 = 0; o4 < 8; ++o4) {
        float y[4];
        #pragma unroll
        for (int j = 0; j < 4; ++j) {
            int o = o4 * 4 + j;
            float s = gamma[o] * rsqrtf(var[o] + BN_EPS);
            float b = beta[o] - mean[o] * s;
            y[j] = fmaxf(fmaf(acc[o], s, b), 0.f);
        }
        if (ADD) {
            float4 prev = *reinterpret_cast<const float4*>(orow + o4*4);
            y[0] += prev.x; y[1] += prev.y; y[2] += prev.z; y[3] += prev.w;
        }
        float4 r; r.x = y[0]; r.y = y[1]; r.z = y[2]; r.w = y[3];
        *reinterpret_cast<float4*>(orow + o4*4) = r;
    }
}

extern "C" void kernel_launch(void* const* d_in, const int* in_sizes, int n_in,
                              void* d_out, int out_size, void* d_ws, size_t ws_size,
                              hipStream_t stream) {
    const float* features = (const float*)d_in[0];
    const int*   nbr13    = (const int*)  d_in[1];
    const int*   nbr31    = (const int*)  d_in[2];
    const float* w1       = (const float*)d_in[3];
    const float* w12      = (const float*)d_in[4];
    const float* w2       = (const float*)d_in[5];
    const float* w3       = (const float*)d_in[6];
    const float* gamma    = (const float*)d_in[7];  // [4][32]
    const float* beta     = (const float*)d_in[8];
    const float* mean     = (const float*)d_in[9];
    const float* var      = (const float*)d_in[10];
    float* out = (float*)d_out;
    float* ws0 = (float*)d_ws;    // one [NPTS][32] f32 scratch = 51.2 MB

    dim3 grid((NPTS + 255) / 256), block(256);

    // shortcut: sc1 = BNReLU0(conv(features, nbr13, w1)) -> ws0
    conv_bn_relu<16, false><<<grid, block, 0, stream>>>(
        features, nbr13, w1, gamma + 0, beta + 0, mean + 0, var + 0, ws0);
    // sc = BNReLU1(conv(sc1, nbr31, w12)) -> d_out (used as temp)
    conv_bn_relu<32, false><<<grid, block, 0, stream>>>(
        ws0, nbr31, w12, gamma + 32, beta + 32, mean + 32, var + 32, out);
    // main: t = BNReLU2(conv(features, nbr31, w2)) -> ws0 (overwrite, k2 done)
    conv_bn_relu<16, false><<<grid, block, 0, stream>>>(
        features, nbr31, w2, gamma + 64, beta + 64, mean + 64, var + 64, ws0);
    // out = BNReLU3(conv(t, nbr13, w3)) + sc   (reads own row of d_out, no race)
    conv_bn_relu<32, true><<<grid, block, 0, stream>>>(
        ws0, nbr13, w3, gamma + 96, beta + 96, mean + 96, var + 96, out);
}